// Round 5
// baseline (2865.401 us; speedup 1.0000x reference)
//
#include <hip/hip_runtime.h>

#define NN 100000
#define EE 1600000
#define IN_F 24
#define HID 128
#define OUT_F 12
#define HC 256          // hcat row width in bf16: [h (128) | aggn (128)]
#define LBLK 128        // rows per layer-GEMM block

#define DEG_WIN 16384   // nodes per out-deg window (64KB u32 LDS)
#define DEG_GRP 7       // ceil(NN/DEG_WIN)
#define DEG_BPG 48      // block-copies per window
#define DEG_BLKS (DEG_GRP * DEG_BPG)   // 336

#define NBKT 782        // dst buckets of 128 nodes: ceil(NN/128)
#define PA_BLKS 512     // bucket-sort blocks
#define PA_EPB 3125     // EE / PA_BLKS

#define EMB_B 2048
#define PREP_B 264      // (65536 + 2048)/256
#define K1_GRID (DEG_BLKS + PA_BLKS + EMB_B + PREP_B)   // 3160

typedef unsigned short u16;
typedef unsigned int u32;
typedef unsigned long long u64;

using short8 = __attribute__((ext_vector_type(8))) short;
using f32x4  = __attribute__((ext_vector_type(4))) float;

__device__ __forceinline__ float bf2f(u16 h) {
  return __uint_as_float(((u32)h) << 16);
}
__device__ __forceinline__ u16 f2bf(float f) {
  u32 u = __float_as_uint(f);
  u32 r = (u + 0x7FFFu + ((u >> 16) & 1u)) >> 16;   // RNE
  return (u16)r;
}
__device__ __forceinline__ float inv_sqrt_cnt(int c) {
  if (c < 1) c = 1;
  return 1.0f / sqrtf((float)c);
}

// ---------- K1 sub-bodies ----------
__device__ __forceinline__ void emb_body(int eb, const float* __restrict__ inputs,
                                         const float* __restrict__ W_emb,
                                         const float* __restrict__ b_emb,
                                         u16* __restrict__ hcat, float* smemW) {
  int t = threadIdx.x;
  float* Wls = smemW;
  float* bls = smemW + IN_F * HID;
  for (int i = t; i < IN_F * HID; i += 256) Wls[i] = W_emb[i];
  if (t < HID) bls[t] = b_emb[t];
  __syncthreads();
  int c = t & 127;
  int sub = t >> 7;
  for (int node = eb * 2 + sub; node < NN; node += EMB_B * 2) {
    const float* xr = inputs + (size_t)node * IN_F;
    float acc = bls[c];
    #pragma unroll
    for (int k = 0; k < IN_F; ++k) acc = fmaf(xr[k], Wls[k * HID + c], acc);
    hcat[(size_t)node * HC + c] = f2bf(acc);
  }
}

__device__ __forceinline__ void prep_body(int pb,
    const float* __restrict__ Ws1, const float* __restrict__ W1m,
    const float* __restrict__ Ws2, const float* __restrict__ W2m,
    const float* __restrict__ Wfc,
    u16* __restrict__ WT1, u16* __restrict__ WT2, u16* __restrict__ WfcT) {
  int idx = pb * 256 + (int)threadIdx.x;
  if (idx < 65536) {
    int layer = idx >> 15;
    int rem = idx & 32767;
    int n = rem >> 8, k = rem & 255;
    const float* A = layer ? Ws2 : Ws1;
    const float* B = layer ? W2m : W1m;
    float v = (k < HID) ? A[(size_t)k * HID + n] : B[(size_t)(k - HID) * HID + n];
    (layer ? WT2 : WT1)[(size_t)n * 256 + k] = f2bf(v);
  } else if (idx < 65536 + 2048) {
    int j = idx - 65536;
    int n = j >> 7, k = j & 127;
    WfcT[(size_t)n * 128 + k] = f2bf(n < OUT_F ? Wfc[(size_t)k * OUT_F + n] : 0.f);
  }
}

// K1: fused [out-deg windowed LDS hist | bucket-count passA | emb | weight prep]
// ZERO global atomics.
__global__ __launch_bounds__(256) void k1(
    const int* __restrict__ src, const int* __restrict__ dst,
    u16* __restrict__ whist, u32* __restrict__ histg,
    const float* __restrict__ inputs, const float* __restrict__ W_emb,
    const float* __restrict__ b_emb, u16* __restrict__ hcat,
    const float* __restrict__ Ws1, const float* __restrict__ W1m,
    const float* __restrict__ Ws2, const float* __restrict__ W2m,
    const float* __restrict__ Wfc,
    u16* __restrict__ WT1, u16* __restrict__ WT2, u16* __restrict__ WfcT) {
  __shared__ __align__(16) char sm_raw[65536];
  int b = blockIdx.x, t = threadIdx.x;
  if (b < DEG_BLKS) {
    // out-degree: window g of 16384 nodes, slice sb of the edge list
    u32* hist = (u32*)sm_raw;
    int g = b / DEG_BPG, sb = b % DEG_BPG;
    for (int i = t; i < DEG_WIN; i += 256) hist[i] = 0;
    __syncthreads();
    for (int e = sb * 256 + t; e < EE; e += DEG_BPG * 256) {
      int s = src[e];
      if ((s >> 14) == g) atomicAdd(&hist[s & (DEG_WIN - 1)], 1u);
    }
    __syncthreads();
    u16* wout = whist + (size_t)b * DEG_WIN;
    for (int i = t; i < DEG_WIN; i += 256) wout[i] = (u16)hist[i];
  } else if (b < DEG_BLKS + PA_BLKS) {
    // passA: per-block bucket counts (dst>>7)
    u32* hist = (u32*)sm_raw;
    int pb = b - DEG_BLKS;
    for (int i = t; i < 1024; i += 256) hist[i] = 0;
    __syncthreads();
    int e0 = pb * PA_EPB;
    for (int e = e0 + t; e < e0 + PA_EPB; e += 256)
      atomicAdd(&hist[dst[e] >> 7], 1u);
    __syncthreads();
    for (int i = t; i < 1024; i += 256) histg[(size_t)pb * 1024 + i] = hist[i];
  } else if (b < DEG_BLKS + PA_BLKS + EMB_B) {
    emb_body(b - DEG_BLKS - PA_BLKS, inputs, W_emb, b_emb, hcat, (float*)sm_raw);
  } else {
    prep_body(b - DEG_BLKS - PA_BLKS - EMB_B, Ws1, W1m, Ws2, W2m, Wfc, WT1, WT2, WfcT);
  }
}

// K2: merge deg copies -> out_norm
__global__ __launch_bounds__(256) void k2(const u16* __restrict__ whist,
                                          float* __restrict__ out_norm) {
  int n = blockIdx.x * 256 + (int)threadIdx.x;
  if (n >= NN) return;
  int g = n >> 14, i = n & (DEG_WIN - 1);
  const u16* base = whist + ((size_t)g * DEG_BPG) * DEG_WIN + i;
  u32 s = 0;
  #pragma unroll
  for (int bb = 0; bb < DEG_BPG; ++bb) s += base[(size_t)bb * DEG_WIN];
  out_norm[n] = inv_sqrt_cnt((int)s);
}

// scan1: per bucket k, exclusive scan over the 512 passA blocks (in-place) + total
__global__ __launch_bounds__(256) void k_scan1(u32* __restrict__ histg,
                                               u32* __restrict__ totals) {
  __shared__ u32 s[512];
  int k = blockIdx.x, t = threadIdx.x;
  u32 v0 = histg[(size_t)t * 1024 + k];
  u32 v1 = histg[(size_t)(t + 256) * 1024 + k];
  s[t] = v0; s[t + 256] = v1;
  __syncthreads();
  for (int off = 1; off < 512; off <<= 1) {
    u32 a0 = (t >= off) ? s[t - off] : 0;
    u32 a1 = (t + 256 >= off) ? s[t + 256 - off] : 0;
    __syncthreads();
    s[t] += a0; s[t + 256] += a1;
    __syncthreads();
  }
  histg[(size_t)t * 1024 + k] = s[t] - v0;              // exclusive prefix
  histg[(size_t)(t + 256) * 1024 + k] = s[t + 256] - v1;
  if (t == 255) totals[k] = s[511];
}

// scan2: exclusive scan over bucket totals -> estart[0..NBKT]
__global__ __launch_bounds__(1024) void k_scan2(const u32* __restrict__ totals,
                                                u32* __restrict__ estart) {
  __shared__ u32 s[1024];
  int t = threadIdx.x;
  u32 v = (t < NBKT) ? totals[t] : 0;
  s[t] = v;
  __syncthreads();
  for (int off = 1; off < 1024; off <<= 1) {
    u32 a = (t >= off) ? s[t - off] : 0;
    __syncthreads();
    s[t] += a;
    __syncthreads();
  }
  if (t < NBKT) estart[t] = s[t] - v;
  if (t == NBKT - 1) estart[NBKT] = s[t];
}

// passB: scatter edges to bucket-ordered ebuf via LDS cursors (no global atomics)
__global__ __launch_bounds__(256) void k_passb(
    const int* __restrict__ src, const int* __restrict__ dst,
    const float* __restrict__ e_w, const float* __restrict__ out_norm,
    const u32* __restrict__ histg, const u32* __restrict__ estart,
    u64* __restrict__ ebuf) {
  __shared__ u32 cur[1024];
  int pb = blockIdx.x, t = threadIdx.x;
  for (int i = t; i < 1024; i += 256) {
    u32 c = histg[(size_t)pb * 1024 + i];
    cur[i] = ((i < NBKT) ? estart[i] : 0u) + c;
  }
  __syncthreads();
  int e0 = pb * PA_EPB;
  for (int e = e0 + t; e < e0 + PA_EPB; e += 256) {
    int s = src[e], d = dst[e];
    float w = e_w[e] * out_norm[s];
    u32 pos = atomicAdd(&cur[d >> 7], 1u);   // LDS atomic
    ebuf[pos] = ((u64)(u32)(d & 127) << 32) | (u64)((((u32)f2bf(w)) << 17) | (u32)s);
  }
}

// agg: per bucket (128 dst nodes), LDS f32 accumulation + in-deg count.
// writes hcat aggn cols and in_norm_g.
__global__ __launch_bounds__(256) void k_agg(const u16* __restrict__ hcat_in,
                                             const u64* __restrict__ ebuf,
                                             const u32* __restrict__ estart,
                                             float* __restrict__ in_norm_g,
                                             u16* __restrict__ hcat_out) {
  __shared__ __align__(16) float acc[128][2][64];   // [dl][k][lane] ; col = 2*lane + k
  __shared__ u32 cnt[128];
  __shared__ float innf[128];
  int k = blockIdx.x, t = threadIdx.x;
  for (int i = t; i < 128 * 128; i += 256) ((float*)acc)[i] = 0.f;
  if (t < 128) cnt[t] = 0;
  __syncthreads();
  int e0 = (int)estart[k], e1 = (int)estart[k + 1];
  int l = t & 63, wv = t >> 6;
  for (int base = e0 + wv * 4; base < e1; base += 16) {
    #pragma unroll
    for (int j = 0; j < 4; ++j) {
      int e = base + j;
      if (e < e1) {
        u64 ed = ebuf[e];
        int dl = (int)(ed >> 32);
        u32 lo = (u32)ed;
        float ww = bf2f((u16)(lo >> 17));
        int sv = (int)(lo & 0x1FFFF);
        ushort2 hv = *(const ushort2*)(hcat_in + (size_t)sv * HC + 2 * l);
        atomicAdd(&acc[dl][0][l], bf2f(hv.x) * ww);
        atomicAdd(&acc[dl][1][l], bf2f(hv.y) * ww);
        if (l == j) atomicAdd(&cnt[dl], 1u);
      }
    }
  }
  __syncthreads();
  if (t < 128) {
    int node = k * 128 + t;
    float inn = inv_sqrt_cnt((int)cnt[t]);
    innf[t] = inn;
    if (node < NN) in_norm_g[node] = inn;
  }
  __syncthreads();
  int r = t >> 1, ch = t & 1;
  int node = k * 128 + r;
  if (node < NN) {
    float inn = innf[r];
    #pragma unroll
    for (int q = 0; q < 8; ++q) {
      union { u16 h[8]; uint4 v; } pk;
      #pragma unroll
      for (int x = 0; x < 8; ++x) {
        int c = ch * 64 + q * 8 + x;
        pk.h[x] = f2bf(acc[r][c & 1][c >> 1] * inn);
      }
      *(uint4*)(hcat_out + (size_t)node * HC + 128 + ch * 64 + q * 8) = pk.v;
    }
  }
}

// ---------- MFMA layer GEMM (128x128, K=256), optional fused FC ----------
template<int FC>
__global__ __launch_bounds__(512) void k_layer(u16* __restrict__ hcat,
    const u16* __restrict__ WT, const float* __restrict__ bias,
    const float* __restrict__ in_norm,
    const u16* __restrict__ WfcT, const float* __restrict__ b_fc,
    float* __restrict__ out) {
  __shared__ char smem[135168];
  const int t = threadIdx.x;
  const int r0 = blockIdx.x * LBLK;

  #pragma unroll
  for (int i = 0; i < 8; ++i) {      // stage X (64KB); tail OOB rows land in WT scratch, benign
    int boff = i * 8192 + t * 16;
    int row = boff >> 9, col = boff & 511;
    uint4 v = *(const uint4*)(hcat + (size_t)(r0 + row) * HC + (col >> 1));
    *(uint4*)(smem + row * 512 + (col ^ ((row & 7) << 4))) = v;
  }
  #pragma unroll
  for (int i = 0; i < 8; ++i) {      // stage W (64KB)
    int boff = i * 8192 + t * 16;
    int row = boff >> 9, col = boff & 511;
    uint4 v = *(const uint4*)(WT + (size_t)row * 256 + (col >> 1));
    *(uint4*)(smem + 65536 + row * 512 + (col ^ ((row & 7) << 4))) = v;
  }
  if (FC && t < 256) {               // stage WfcT (4KB)
    int row = t >> 4, col = (t & 15) * 16;
    uint4 v = *(const uint4*)(WfcT + (size_t)row * 128 + (col >> 1));
    *(uint4*)(smem + 131072 + row * 256 + (col ^ ((row & 7) << 4))) = v;
  }
  __syncthreads();

  const int lane = t & 63, w = t >> 6;
  const int l15 = lane & 15, lhi = lane >> 4;

  f32x4 acc[8];
  #pragma unroll
  for (int nf = 0; nf < 8; ++nf) acc[nf] = (f32x4){0.f, 0.f, 0.f, 0.f};

  const int arow = w * 16 + l15;
  const char* pa = smem + arow * 512;
  const int aswz = (arow & 7) << 4;
  #pragma unroll
  for (int ks = 0; ks < 8; ++ks) {
    int kb = ks * 64 + (lhi << 4);
    short8 a = *(const short8*)(pa + (kb ^ aswz));
    #pragma unroll
    for (int nf = 0; nf < 8; ++nf) {
      int brow = nf * 16 + l15;
      short8 bf = *(const short8*)(smem + 65536 + brow * 512 + (kb ^ ((brow & 7) << 4)));
      acc[nf] = __builtin_amdgcn_mfma_f32_16x16x32_bf16(a, bf, acc[nf], 0, 0, 0);
    }
  }

  float bcol[8];
  #pragma unroll
  for (int nf = 0; nf < 8; ++nf) bcol[nf] = bias[nf * 16 + l15];

  if (!FC) {
    #pragma unroll
    for (int r = 0; r < 4; ++r) {
      int grow = r0 + w * 16 + (lhi << 2) + r;
      if (grow < NN) {
        float inn = in_norm[grow];
        #pragma unroll
        for (int nf = 0; nf < 8; ++nf) {
          float v = acc[nf][r] + inn * bcol[nf];
          hcat[(size_t)grow * HC + nf * 16 + l15] = f2bf(fmaxf(v, 0.f));
        }
      }
    }
  } else {
    #pragma unroll
    for (int r = 0; r < 4; ++r) {
      int lrow = w * 16 + (lhi << 2) + r;
      int grow = r0 + lrow;
      float inn = (grow < NN) ? in_norm[grow] : 0.f;
      #pragma unroll
      for (int nf = 0; nf < 8; ++nf) {
        int col = nf * 16 + l15;
        float v = fmaxf(acc[nf][r] + inn * bcol[nf], 0.f);
        *(u16*)(smem + lrow * 256 + ((col * 2) ^ ((lrow & 7) << 4))) = f2bf(v);
      }
    }
    __syncthreads();
    f32x4 a2 = (f32x4){0.f, 0.f, 0.f, 0.f};
    const char* pa2 = smem + (w * 16 + l15) * 256;
    const int as2 = (l15 & 7) << 4;
    #pragma unroll
    for (int ks = 0; ks < 4; ++ks) {
      int kb = ks * 64 + (lhi << 4);
      short8 a = *(const short8*)(pa2 + (kb ^ as2));
      short8 bf = *(const short8*)(smem + 131072 + l15 * 256 + (kb ^ as2));
      a2 = __builtin_amdgcn_mfma_f32_16x16x32_bf16(a, bf, a2, 0, 0, 0);
    }
    if (l15 < OUT_F) {
      float bo = b_fc[l15];
      #pragma unroll
      for (int r = 0; r < 4; ++r) {
        int grow = r0 + w * 16 + (lhi << 2) + r;
        if (grow < NN) out[(size_t)grow * OUT_F + l15] = a2[r] + bo;
      }
    }
  }
}

extern "C" void kernel_launch(void* const* d_in, const int* in_sizes, int n_in,
                              void* d_out, int out_size, void* d_ws, size_t ws_size,
                              hipStream_t stream) {
  (void)in_sizes; (void)n_in; (void)out_size;
  const float* inputs  = (const float*)d_in[0];
  const int*   src     = (const int*)d_in[1];
  const int*   dst     = (const int*)d_in[2];
  const float* e_w     = (const float*)d_in[3];
  const float* W_emb   = (const float*)d_in[6];
  const float* b_emb   = (const float*)d_in[7];
  const float* W_self1 = (const float*)d_in[8];
  const float* W1      = (const float*)d_in[9];
  const float* b1      = (const float*)d_in[10];
  const float* W_self2 = (const float*)d_in[11];
  const float* W2      = (const float*)d_in[12];
  const float* b2      = (const float*)d_in[13];
  const float* W_fc    = (const float*)d_in[14];
  const float* b_fc    = (const float*)d_in[15];
  float* out = (float*)d_out;

  // layout (67.0 MB total, < proven 72.2 MB):
  // [ebuf u64 EE (12.8M) | histg u32 512*1024 (2M) | totals 1024 | estart 1024
  //  | out_norm NN | in_norm NN | hcat NN*HC u16 (51.2M) | WT1 | WT2 | WfcT]
  // whist (u16, 336*16384 = 11.0 MB) overlays ebuf — dead before passB writes ebuf.
  u64* ebuf        = (u64*)d_ws;
  u16* whist       = (u16*)d_ws;
  u32* histg       = (u32*)(ebuf + EE);
  u32* totals      = histg + (size_t)512 * 1024;
  u32* estart      = totals + 1024;
  float* out_norm  = (float*)(estart + 1024);
  float* in_norm_g = out_norm + NN;
  u16* hcat        = (u16*)(in_norm_g + NN);
  u16* WT1         = hcat + (size_t)NN * HC;
  u16* WT2         = WT1 + 32768;
  u16* WfcT        = WT2 + 32768;

  const size_t NEED = (size_t)EE * 8 + (size_t)512 * 1024 * 4 + 2048 * 4
                      + (size_t)2 * NN * 4 + (size_t)NN * HC * 2 + (2 * 32768 + 2048) * 2;
  if (ws_size < NEED) return;

  hipLaunchKernelGGL(k1, dim3(K1_GRID), dim3(256), 0, stream,
                     src, dst, whist, histg, inputs, W_emb, b_emb, hcat,
                     W_self1, W1, W_self2, W2, W_fc, WT1, WT2, WfcT);
  hipLaunchKernelGGL(k2, dim3((NN + 255) / 256), dim3(256), 0, stream, whist, out_norm);
  hipLaunchKernelGGL(k_scan1, dim3(NBKT), dim3(256), 0, stream, histg, totals);
  hipLaunchKernelGGL(k_scan2, dim3(1), dim3(1024), 0, stream, totals, estart);
  hipLaunchKernelGGL(k_passb, dim3(PA_BLKS), dim3(256), 0, stream,
                     src, dst, e_w, out_norm, histg, estart, ebuf);
  // layer 1
  hipLaunchKernelGGL(k_agg, dim3(NBKT), dim3(256), 0, stream,
                     hcat, ebuf, estart, in_norm_g, hcat);
  hipLaunchKernelGGL(k_layer<0>, dim3((NN + LBLK - 1) / LBLK), dim3(512), 0, stream,
                     hcat, WT1, b1, in_norm_g, WfcT, b_fc, out);
  // layer 2 + fused FC
  hipLaunchKernelGGL(k_agg, dim3(NBKT), dim3(256), 0, stream,
                     hcat, ebuf, estart, in_norm_g, hcat);
  hipLaunchKernelGGL(k_layer<1>, dim3((NN + LBLK - 1) / LBLK), dim3(512), 0, stream,
                     hcat, WT2, b2, in_norm_g, WfcT, b_fc, out);
}

// Round 6
// 389.292 us; speedup vs baseline: 7.3605x; 7.3605x over previous
//
#include <hip/hip_runtime.h>

#define NN 100000
#define EE 1600000
#define IN_F 24
#define HID 128
#define OUT_F 12
#define HC 256          // hcat row width in bf16: [h (128) | aggn (128)]
#define LBLK 128        // rows per layer-GEMM block

#define DEG_WIN 16384   // nodes per out-deg window (64KB u32 LDS)
#define DEG_GRP 7       // ceil(NN/DEG_WIN)
#define DEG_BPG 48      // block-copies per window
#define DEG_BLKS (DEG_GRP * DEG_BPG)   // 336

#define NBKT 782        // dst buckets of 128 nodes: ceil(NN/128)
#define PA_BLKS 512     // bucket-sort blocks
#define PA_EPB 3125     // EE / PA_BLKS

#define EMB_B 2048
#define PREP_B 264      // (65536 + 2048)/256
#define K1_GRID (DEG_BLKS + PA_BLKS + EMB_B + PREP_B)   // 3160

typedef unsigned char u8;
typedef unsigned short u16;
typedef unsigned int u32;

using short8 = __attribute__((ext_vector_type(8))) short;
using f32x4  = __attribute__((ext_vector_type(4))) float;

__device__ __forceinline__ float bf2f(u16 h) {
  return __uint_as_float(((u32)h) << 16);
}
__device__ __forceinline__ u16 f2bf(float f) {
  u32 u = __float_as_uint(f);
  u32 r = (u + 0x7FFFu + ((u >> 16) & 1u)) >> 16;   // RNE
  return (u16)r;
}
__device__ __forceinline__ float inv_sqrt_cnt(int c) {
  if (c < 1) c = 1;
  return 1.0f / sqrtf((float)c);
}

// ---------- K1 sub-bodies ----------
__device__ __forceinline__ void emb_body(int eb, const float* __restrict__ inputs,
                                         const float* __restrict__ W_emb,
                                         const float* __restrict__ b_emb,
                                         u16* __restrict__ hcat, float* smemW) {
  int t = threadIdx.x;
  float* Wls = smemW;
  float* bls = smemW + IN_F * HID;
  for (int i = t; i < IN_F * HID; i += 256) Wls[i] = W_emb[i];
  if (t < HID) bls[t] = b_emb[t];
  __syncthreads();
  int c = t & 127;
  int sub = t >> 7;
  for (int node = eb * 2 + sub; node < NN; node += EMB_B * 2) {
    const float* xr = inputs + (size_t)node * IN_F;
    float acc = bls[c];
    #pragma unroll
    for (int k = 0; k < IN_F; ++k) acc = fmaf(xr[k], Wls[k * HID + c], acc);
    hcat[(size_t)node * HC + c] = f2bf(acc);
  }
}

__device__ __forceinline__ void prep_body(int pb,
    const float* __restrict__ Ws1, const float* __restrict__ W1m,
    const float* __restrict__ Ws2, const float* __restrict__ W2m,
    const float* __restrict__ Wfc,
    u16* __restrict__ WT1, u16* __restrict__ WT2, u16* __restrict__ WfcT) {
  int idx = pb * 256 + (int)threadIdx.x;
  if (idx < 65536) {
    int layer = idx >> 15;
    int rem = idx & 32767;
    int n = rem >> 8, k = rem & 255;
    const float* A = layer ? Ws2 : Ws1;
    const float* B = layer ? W2m : W1m;
    float v = (k < HID) ? A[(size_t)k * HID + n] : B[(size_t)(k - HID) * HID + n];
    (layer ? WT2 : WT1)[(size_t)n * 256 + k] = f2bf(v);
  } else if (idx < 65536 + 2048) {
    int j = idx - 65536;
    int n = j >> 7, k = j & 127;
    WfcT[(size_t)n * 128 + k] = f2bf(n < OUT_F ? Wfc[(size_t)k * OUT_F + n] : 0.f);
  }
}

// K1: fused [out-deg windowed LDS hist | bucket-count passA | emb | weight prep]
// ZERO global atomics.
__global__ __launch_bounds__(256) void k1(
    const int* __restrict__ src, const int* __restrict__ dst,
    u16* __restrict__ whist, u32* __restrict__ histg,
    const float* __restrict__ inputs, const float* __restrict__ W_emb,
    const float* __restrict__ b_emb, u16* __restrict__ hcat,
    const float* __restrict__ Ws1, const float* __restrict__ W1m,
    const float* __restrict__ Ws2, const float* __restrict__ W2m,
    const float* __restrict__ Wfc,
    u16* __restrict__ WT1, u16* __restrict__ WT2, u16* __restrict__ WfcT) {
  __shared__ __align__(16) char sm_raw[65536];
  int b = blockIdx.x, t = threadIdx.x;
  if (b < DEG_BLKS) {
    u32* hist = (u32*)sm_raw;
    int g = b / DEG_BPG, sb = b % DEG_BPG;
    for (int i = t; i < DEG_WIN; i += 256) hist[i] = 0;
    __syncthreads();
    for (int e = sb * 256 + t; e < EE; e += DEG_BPG * 256) {
      int s = src[e];
      if ((s >> 14) == g) atomicAdd(&hist[s & (DEG_WIN - 1)], 1u);
    }
    __syncthreads();
    u16* wout = whist + (size_t)b * DEG_WIN;
    for (int i = t; i < DEG_WIN; i += 256) wout[i] = (u16)hist[i];
  } else if (b < DEG_BLKS + PA_BLKS) {
    u32* hist = (u32*)sm_raw;
    int pb = b - DEG_BLKS;
    for (int i = t; i < 1024; i += 256) hist[i] = 0;
    __syncthreads();
    int e0 = pb * PA_EPB;
    for (int e = e0 + t; e < e0 + PA_EPB; e += 256)
      atomicAdd(&hist[dst[e] >> 7], 1u);
    __syncthreads();
    for (int i = t; i < 1024; i += 256) histg[(size_t)pb * 1024 + i] = hist[i];
  } else if (b < DEG_BLKS + PA_BLKS + EMB_B) {
    emb_body(b - DEG_BLKS - PA_BLKS, inputs, W_emb, b_emb, hcat, (float*)sm_raw);
  } else {
    prep_body(b - DEG_BLKS - PA_BLKS - EMB_B, Ws1, W1m, Ws2, W2m, Wfc, WT1, WT2, WfcT);
  }
}

// fused [scan1 over passA blocks | out-deg merge -> out_norm]
__global__ __launch_bounds__(256) void k2scan1(const u16* __restrict__ whist,
                                               float* __restrict__ out_norm,
                                               u32* __restrict__ histg,
                                               u32* __restrict__ totals) {
  __shared__ u32 s[512];
  int b = blockIdx.x, t = threadIdx.x;
  if (b < NBKT) {
    int k = b;
    u32 v0 = histg[(size_t)t * 1024 + k];
    u32 v1 = histg[(size_t)(t + 256) * 1024 + k];
    s[t] = v0; s[t + 256] = v1;
    __syncthreads();
    for (int off = 1; off < 512; off <<= 1) {
      u32 a0 = (t >= off) ? s[t - off] : 0;
      u32 a1 = (t + 256 >= off) ? s[t + 256 - off] : 0;
      __syncthreads();
      s[t] += a0; s[t + 256] += a1;
      __syncthreads();
    }
    histg[(size_t)t * 1024 + k] = s[t] - v0;              // exclusive prefix
    histg[(size_t)(t + 256) * 1024 + k] = s[t + 256] - v1;
    if (t == 255) totals[k] = s[511];
  } else {
    int n = (b - NBKT) * 256 + t;
    if (n < NN) {
      int g = n >> 14, i = n & (DEG_WIN - 1);
      const u16* base = whist + ((size_t)g * DEG_BPG) * DEG_WIN + i;
      u32 sum = 0;
      #pragma unroll
      for (int bb = 0; bb < DEG_BPG; ++bb) sum += base[(size_t)bb * DEG_WIN];
      out_norm[n] = inv_sqrt_cnt((int)sum);
    }
  }
}

// scan2: exclusive scan over bucket totals -> estart[0..NBKT]
__global__ __launch_bounds__(1024) void k_scan2(const u32* __restrict__ totals,
                                                u32* __restrict__ estart) {
  __shared__ u32 s[1024];
  int t = threadIdx.x;
  u32 v = (t < NBKT) ? totals[t] : 0;
  s[t] = v;
  __syncthreads();
  for (int off = 1; off < 1024; off <<= 1) {
    u32 a = (t >= off) ? s[t - off] : 0;
    __syncthreads();
    s[t] += a;
    __syncthreads();
  }
  if (t < NBKT) estart[t] = s[t] - v;
  if (t == NBKT - 1) estart[NBKT] = s[t];
}

// passB: scatter edges to bucket-ordered arrays via LDS cursors (no global atomics)
__global__ __launch_bounds__(256) void k_passb(
    const int* __restrict__ src, const int* __restrict__ dst,
    const float* __restrict__ e_w, const float* __restrict__ out_norm,
    const u32* __restrict__ histg, const u32* __restrict__ estart,
    u32* __restrict__ csr_stage, u8* __restrict__ dl8) {
  __shared__ u32 cur[1024];
  int pb = blockIdx.x, t = threadIdx.x;
  for (int i = t; i < 1024; i += 256)
    cur[i] = ((i < NBKT) ? estart[i] : 0u) + histg[(size_t)pb * 1024 + i];
  __syncthreads();
  int e0 = pb * PA_EPB;
  for (int e = e0 + t; e < e0 + PA_EPB; e += 256) {
    int s = src[e], d = dst[e];
    float w = e_w[e] * out_norm[s];          // w in (0,1] -> bf16 fits 15 bits
    u32 pos = atomicAdd(&cur[d >> 7], 1u);   // LDS atomic
    csr_stage[pos] = (((u32)f2bf(w)) << 17) | (u32)s;
    dl8[pos] = (u8)(d & 127);
  }
}

// within-bucket counting sort -> per-node CSR + row_start + in_norm (no global atomics)
__global__ __launch_bounds__(256) void k_reorder(
    const u32* __restrict__ csr_stage, const u8* __restrict__ dl8,
    const u32* __restrict__ estart, u32* __restrict__ csr,
    int* __restrict__ row_start, float* __restrict__ in_norm) {
  __shared__ u32 cnt[128], pfx[128], cur[128];
  int k = blockIdx.x, t = threadIdx.x;
  if (t < 128) cnt[t] = 0;
  __syncthreads();
  int e0 = (int)estart[k], e1 = (int)estart[k + 1];
  for (int e = e0 + t; e < e1; e += 256) atomicAdd(&cnt[dl8[e]], 1u);
  __syncthreads();
  if (t < 128) pfx[t] = cnt[t];
  __syncthreads();
  for (int off = 1; off < 128; off <<= 1) {
    u32 v = (t < 128 && t >= off) ? pfx[t - off] : 0;
    __syncthreads();
    if (t < 128) pfx[t] += v;
    __syncthreads();
  }
  if (t < 128) {
    u32 start = (u32)e0 + pfx[t] - cnt[t];   // exclusive
    cur[t] = start;
    int node = k * 128 + t;
    if (node < NN) {
      row_start[node] = (int)start;
      in_norm[node] = inv_sqrt_cnt((int)cnt[t]);
    }
  }
  if (k == NBKT - 1 && t == 0) row_start[NN] = e1;
  __syncthreads();
  for (int e = e0 + t; e < e1; e += 256) {
    u32 pos = atomicAdd(&cur[dl8[e]], 1u);
    csr[pos] = csr_stage[e];
  }
}

// agg (round-3 proven gather form): aggn[d] = in_norm[d] * sum w_packed * h[src]
__global__ __launch_bounds__(256) void k_agg(const u16* __restrict__ hcat_in,
                                             const int* __restrict__ row_start,
                                             const float* __restrict__ in_norm,
                                             const u32* __restrict__ csr,
                                             u16* __restrict__ hcat_out) {
  int t = threadIdx.x;
  int node = blockIdx.x * 8 + (t >> 5);
  if (node >= NN) return;
  int lane = t & 31;
  int s0 = row_start[node], s1 = row_start[node + 1];
  float ax = 0.f, ay = 0.f, az = 0.f, aw = 0.f;
  for (int i0 = s0; i0 < s1; i0 += 32) {
    u32 pk = 0;
    if (i0 + lane < s1) pk = csr[i0 + lane];
    int m = s1 - i0; if (m > 32) m = 32;
    for (int j = 0; j < m; ++j) {
      u32 p = __shfl(pk, j, 32);
      float w = bf2f((u16)(p >> 17));
      int sv = (int)(p & 0x1FFFF);
      ushort4 hv = *(const ushort4*)(hcat_in + (size_t)sv * HC + lane * 4);
      ax = fmaf(w, bf2f(hv.x), ax);
      ay = fmaf(w, bf2f(hv.y), ay);
      az = fmaf(w, bf2f(hv.z), az);
      aw = fmaf(w, bf2f(hv.w), aw);
    }
  }
  float inn = in_norm[node];
  ushort4 r;
  r.x = f2bf(ax * inn); r.y = f2bf(ay * inn);
  r.z = f2bf(az * inn); r.w = f2bf(aw * inn);
  *(ushort4*)(hcat_out + (size_t)node * HC + HID + lane * 4) = r;
}

// ---------- MFMA layer GEMM (128x128, K=256), optional fused FC ----------
template<int FC>
__global__ __launch_bounds__(512) void k_layer(u16* __restrict__ hcat,
    const u16* __restrict__ WT, const float* __restrict__ bias,
    const float* __restrict__ in_norm,
    const u16* __restrict__ WfcT, const float* __restrict__ b_fc,
    float* __restrict__ out) {
  __shared__ char smem[135168];
  const int t = threadIdx.x;
  const int r0 = blockIdx.x * LBLK;

  #pragma unroll
  for (int i = 0; i < 8; ++i) {      // stage X (64KB); tail OOB rows land in WT scratch, benign
    int boff = i * 8192 + t * 16;
    int row = boff >> 9, col = boff & 511;
    uint4 v = *(const uint4*)(hcat + (size_t)(r0 + row) * HC + (col >> 1));
    *(uint4*)(smem + row * 512 + (col ^ ((row & 7) << 4))) = v;
  }
  #pragma unroll
  for (int i = 0; i < 8; ++i) {      // stage W (64KB)
    int boff = i * 8192 + t * 16;
    int row = boff >> 9, col = boff & 511;
    uint4 v = *(const uint4*)(WT + (size_t)row * 256 + (col >> 1));
    *(uint4*)(smem + 65536 + row * 512 + (col ^ ((row & 7) << 4))) = v;
  }
  if (FC && t < 256) {               // stage WfcT (4KB)
    int row = t >> 4, col = (t & 15) * 16;
    uint4 v = *(const uint4*)(WfcT + (size_t)row * 128 + (col >> 1));
    *(uint4*)(smem + 131072 + row * 256 + (col ^ ((row & 7) << 4))) = v;
  }
  __syncthreads();

  const int lane = t & 63, w = t >> 6;
  const int l15 = lane & 15, lhi = lane >> 4;

  f32x4 acc[8];
  #pragma unroll
  for (int nf = 0; nf < 8; ++nf) acc[nf] = (f32x4){0.f, 0.f, 0.f, 0.f};

  const int arow = w * 16 + l15;
  const char* pa = smem + arow * 512;
  const int aswz = (arow & 7) << 4;
  #pragma unroll
  for (int ks = 0; ks < 8; ++ks) {
    int kb = ks * 64 + (lhi << 4);
    short8 a = *(const short8*)(pa + (kb ^ aswz));
    #pragma unroll
    for (int nf = 0; nf < 8; ++nf) {
      int brow = nf * 16 + l15;
      short8 bf = *(const short8*)(smem + 65536 + brow * 512 + (kb ^ ((brow & 7) << 4)));
      acc[nf] = __builtin_amdgcn_mfma_f32_16x16x32_bf16(a, bf, acc[nf], 0, 0, 0);
    }
  }

  float bcol[8];
  #pragma unroll
  for (int nf = 0; nf < 8; ++nf) bcol[nf] = bias[nf * 16 + l15];

  if (!FC) {
    #pragma unroll
    for (int r = 0; r < 4; ++r) {
      int grow = r0 + w * 16 + (lhi << 2) + r;
      if (grow < NN) {
        float inn = in_norm[grow];
        #pragma unroll
        for (int nf = 0; nf < 8; ++nf) {
          float v = acc[nf][r] + inn * bcol[nf];
          hcat[(size_t)grow * HC + nf * 16 + l15] = f2bf(fmaxf(v, 0.f));
        }
      }
    }
  } else {
    #pragma unroll
    for (int r = 0; r < 4; ++r) {
      int lrow = w * 16 + (lhi << 2) + r;
      int grow = r0 + lrow;
      float inn = (grow < NN) ? in_norm[grow] : 0.f;
      #pragma unroll
      for (int nf = 0; nf < 8; ++nf) {
        int col = nf * 16 + l15;
        float v = fmaxf(acc[nf][r] + inn * bcol[nf], 0.f);
        *(u16*)(smem + lrow * 256 + ((col * 2) ^ ((lrow & 7) << 4))) = f2bf(v);
      }
    }
    __syncthreads();
    f32x4 a2 = (f32x4){0.f, 0.f, 0.f, 0.f};
    const char* pa2 = smem + (w * 16 + l15) * 256;
    const int as2 = (l15 & 7) << 4;
    #pragma unroll
    for (int ks = 0; ks < 4; ++ks) {
      int kb = ks * 64 + (lhi << 4);
      short8 a = *(const short8*)(pa2 + (kb ^ as2));
      short8 bf = *(const short8*)(smem + 131072 + l15 * 256 + (kb ^ as2));
      a2 = __builtin_amdgcn_mfma_f32_16x16x32_bf16(a, bf, a2, 0, 0, 0);
    }
    if (l15 < OUT_F) {
      float bo = b_fc[l15];
      #pragma unroll
      for (int r = 0; r < 4; ++r) {
        int grow = r0 + w * 16 + (lhi << 2) + r;
        if (grow < NN) out[(size_t)grow * OUT_F + l15] = a2[r] + bo;
      }
    }
  }
}

extern "C" void kernel_launch(void* const* d_in, const int* in_sizes, int n_in,
                              void* d_out, int out_size, void* d_ws, size_t ws_size,
                              hipStream_t stream) {
  (void)in_sizes; (void)n_in; (void)out_size;
  const float* inputs  = (const float*)d_in[0];
  const int*   src     = (const int*)d_in[1];
  const int*   dst     = (const int*)d_in[2];
  const float* e_w     = (const float*)d_in[3];
  const float* W_emb   = (const float*)d_in[6];
  const float* b_emb   = (const float*)d_in[7];
  const float* W_self1 = (const float*)d_in[8];
  const float* W1      = (const float*)d_in[9];
  const float* b1      = (const float*)d_in[10];
  const float* W_self2 = (const float*)d_in[11];
  const float* W2      = (const float*)d_in[12];
  const float* b2      = (const float*)d_in[13];
  const float* W_fc    = (const float*)d_in[14];
  const float* b_fc    = (const float*)d_in[15];
  float* out = (float*)d_out;

  // layout (69.0 MB total, < proven 72.2 MB):
  // [histg 2MB | totals 4KB | estart 4KB | out_norm | in_norm | row_start
  //  | csr_stage u32 EE (6.4M) | dl8 u8 EE (1.6M) | csr u32 EE (6.4M)
  //  | hcat 51.2M | WT1 | WT2 | WfcT]
  // whist (u16, 336*16384 = 11.0MB) overlays csr_stage..csr (14.4MB) — dead before passB.
  u32* histg       = (u32*)d_ws;
  u32* totals      = histg + (size_t)512 * 1024;
  u32* estart      = totals + 1024;
  float* out_norm  = (float*)(estart + 1024);
  float* in_norm   = out_norm + NN;
  int* row_start   = (int*)(in_norm + NN);
  u32* csr_stage   = (u32*)(row_start + NN + 4);
  u8* dl8          = (u8*)(csr_stage + EE);
  u32* csr         = (u32*)(dl8 + EE);
  u16* hcat        = (u16*)(csr + EE);
  u16* WT1         = hcat + (size_t)NN * HC;
  u16* WT2         = WT1 + 32768;
  u16* WfcT        = WT2 + 32768;
  u16* whist       = (u16*)csr_stage;   // overlay

  const size_t NEED = (size_t)512 * 1024 * 4 + 2048 * 4 + (size_t)(3 * NN + 4) * 4
                      + (size_t)EE * 9 + (size_t)NN * HC * 2 + (2 * 32768 + 2048) * 2;
  if (ws_size < NEED) return;

  hipLaunchKernelGGL(k1, dim3(K1_GRID), dim3(256), 0, stream,
                     src, dst, whist, histg, inputs, W_emb, b_emb, hcat,
                     W_self1, W1, W_self2, W2, W_fc, WT1, WT2, WfcT);
  hipLaunchKernelGGL(k2scan1, dim3(NBKT + (NN + 255) / 256), dim3(256), 0, stream,
                     whist, out_norm, histg, totals);
  hipLaunchKernelGGL(k_scan2, dim3(1), dim3(1024), 0, stream, totals, estart);
  hipLaunchKernelGGL(k_passb, dim3(PA_BLKS), dim3(256), 0, stream,
                     src, dst, e_w, out_norm, histg, estart, csr_stage, dl8);
  hipLaunchKernelGGL(k_reorder, dim3(NBKT), dim3(256), 0, stream,
                     csr_stage, dl8, estart, csr, row_start, in_norm);
  // layer 1
  hipLaunchKernelGGL(k_agg, dim3((NN + 7) / 8), dim3(256), 0, stream,
                     hcat, row_start, in_norm, csr, hcat);
  hipLaunchKernelGGL(k_layer<0>, dim3((NN + LBLK - 1) / LBLK), dim3(512), 0, stream,
                     hcat, WT1, b1, in_norm, WfcT, b_fc, out);
  // layer 2 + fused FC
  hipLaunchKernelGGL(k_agg, dim3((NN + 7) / 8), dim3(256), 0, stream,
                     hcat, row_start, in_norm, csr, hcat);
  hipLaunchKernelGGL(k_layer<1>, dim3((NN + LBLK - 1) / LBLK), dim3(512), 0, stream,
                     hcat, WT2, b2, in_norm, WfcT, b_fc, out);
}

// Round 7
// 381.045 us; speedup vs baseline: 7.5198x; 1.0216x over previous
//
#include <hip/hip_runtime.h>

#define NN 100000
#define EE 1600000
#define IN_F 24
#define HID 128
#define OUT_F 12
#define HC 256          // hcat row width in bf16: [h (128) | aggn (128)]
#define LBLK 128        // rows per layer-GEMM block

#define NBKT 782        // node buckets of 128: ceil(NN/128)
#define PA_BLKS 512     // bucket-sort blocks
#define PA_EPB 3125     // EE / PA_BLKS

#define EMB_B 2048
#define PREP_B 264      // (65536 + 2048)/256
#define K1_GRID (PA_BLKS + EMB_B + PREP_B)   // 2824

typedef unsigned char u8;
typedef unsigned short u16;
typedef unsigned int u32;

using short8 = __attribute__((ext_vector_type(8))) short;
using f32x4  = __attribute__((ext_vector_type(4))) float;

__device__ __forceinline__ float bf2f(u16 h) {
  return __uint_as_float(((u32)h) << 16);
}
__device__ __forceinline__ u16 f2bf(float f) {
  u32 u = __float_as_uint(f);
  u32 r = (u + 0x7FFFu + ((u >> 16) & 1u)) >> 16;   // RNE
  return (u16)r;
}
__device__ __forceinline__ float inv_sqrt_cnt(int c) {
  if (c < 1) c = 1;
  return 1.0f / sqrtf((float)c);
}

// ---------- K1 sub-bodies ----------
__device__ __forceinline__ void emb_body(int eb, const float* __restrict__ inputs,
                                         const float* __restrict__ W_emb,
                                         const float* __restrict__ b_emb,
                                         u16* __restrict__ hcat, float* smemW) {
  int t = threadIdx.x;
  float* Wls = smemW;
  float* bls = smemW + IN_F * HID;
  for (int i = t; i < IN_F * HID; i += 256) Wls[i] = W_emb[i];
  if (t < HID) bls[t] = b_emb[t];
  __syncthreads();
  int c = t & 127;
  int sub = t >> 7;
  for (int node = eb * 2 + sub; node < NN; node += EMB_B * 2) {
    const float* xr = inputs + (size_t)node * IN_F;
    float acc = bls[c];
    #pragma unroll
    for (int k = 0; k < IN_F; ++k) acc = fmaf(xr[k], Wls[k * HID + c], acc);
    hcat[(size_t)node * HC + c] = f2bf(acc);
  }
}

__device__ __forceinline__ void prep_body(int pb,
    const float* __restrict__ Ws1, const float* __restrict__ W1m,
    const float* __restrict__ Ws2, const float* __restrict__ W2m,
    const float* __restrict__ Wfc,
    u16* __restrict__ WT1, u16* __restrict__ WT2, u16* __restrict__ WfcT) {
  int idx = pb * 256 + (int)threadIdx.x;
  if (idx < 65536) {
    int layer = idx >> 15;
    int rem = idx & 32767;
    int n = rem >> 8, k = rem & 255;
    const float* A = layer ? Ws2 : Ws1;
    const float* B = layer ? W2m : W1m;
    float v = (k < HID) ? A[(size_t)k * HID + n] : B[(size_t)(k - HID) * HID + n];
    (layer ? WT2 : WT1)[(size_t)n * 256 + k] = f2bf(v);
  } else if (idx < 65536 + 2048) {
    int j = idx - 65536;
    int n = j >> 7, k = j & 127;
    WfcT[(size_t)n * 128 + k] = f2bf(n < OUT_F ? Wfc[(size_t)k * OUT_F + n] : 0.f);
  }
}

// K1: fused [bucket-count passA (dst AND src hists) | emb | weight prep]
// max 13.3 KB LDS -> high occupancy. ZERO global atomics.
__global__ __launch_bounds__(256) void k1(
    const int* __restrict__ src, const int* __restrict__ dst,
    u32* __restrict__ histgD, u32* __restrict__ histgS,
    const float* __restrict__ inputs, const float* __restrict__ W_emb,
    const float* __restrict__ b_emb, u16* __restrict__ hcat,
    const float* __restrict__ Ws1, const float* __restrict__ W1m,
    const float* __restrict__ Ws2, const float* __restrict__ W2m,
    const float* __restrict__ Wfc,
    u16* __restrict__ WT1, u16* __restrict__ WT2, u16* __restrict__ WfcT) {
  __shared__ __align__(16) char sm[13312];
  int b = blockIdx.x, t = threadIdx.x;
  if (b < PA_BLKS) {
    u32* histD = (u32*)sm;
    u32* histS = histD + 1024;
    for (int i = t; i < 2048; i += 256) histD[i] = 0;
    __syncthreads();
    int e0 = b * PA_EPB;
    for (int e = e0 + t; e < e0 + PA_EPB; e += 256) {
      atomicAdd(&histD[dst[e] >> 7], 1u);
      atomicAdd(&histS[src[e] >> 7], 1u);
    }
    __syncthreads();
    for (int i = t; i < 1024; i += 256) {
      histgD[(size_t)b * 1024 + i] = histD[i];
      histgS[(size_t)b * 1024 + i] = histS[i];
    }
  } else if (b < PA_BLKS + EMB_B) {
    emb_body(b - PA_BLKS, inputs, W_emb, b_emb, hcat, (float*)sm);
  } else {
    prep_body(b - PA_BLKS - EMB_B, Ws1, W1m, Ws2, W2m, Wfc, WT1, WT2, WfcT);
  }
}

// scan1: per bucket k (dst for b<NBKT, src otherwise), exclusive scan over 512 blocks
__global__ __launch_bounds__(256) void k_scan1(u32* __restrict__ histgD,
                                               u32* __restrict__ histgS,
                                               u32* __restrict__ totalsD,
                                               u32* __restrict__ totalsS) {
  __shared__ u32 s[512];
  int b = blockIdx.x, t = threadIdx.x;
  u32* hist = (b < NBKT) ? histgD : histgS;
  u32* tot  = (b < NBKT) ? totalsD : totalsS;
  int k = (b < NBKT) ? b : b - NBKT;
  u32 v0 = hist[(size_t)t * 1024 + k];
  u32 v1 = hist[(size_t)(t + 256) * 1024 + k];
  s[t] = v0; s[t + 256] = v1;
  __syncthreads();
  for (int off = 1; off < 512; off <<= 1) {
    u32 a0 = (t >= off) ? s[t - off] : 0;
    u32 a1 = (t + 256 >= off) ? s[t + 256 - off] : 0;
    __syncthreads();
    s[t] += a0; s[t + 256] += a1;
    __syncthreads();
  }
  hist[(size_t)t * 1024 + k] = s[t] - v0;              // exclusive prefix
  hist[(size_t)(t + 256) * 1024 + k] = s[t + 256] - v1;
  if (t == 255) tot[k] = s[511];
}

// scan2: exclusive scan over bucket totals (block 0: dst->estartD, block 1: src->sstart)
__global__ __launch_bounds__(1024) void k_scan2(const u32* __restrict__ totalsD,
                                                const u32* __restrict__ totalsS,
                                                u32* __restrict__ estartD,
                                                u32* __restrict__ sstart) {
  __shared__ u32 s[1024];
  const u32* tot = blockIdx.x ? totalsS : totalsD;
  u32* est       = blockIdx.x ? sstart  : estartD;
  int t = threadIdx.x;
  u32 v = (t < NBKT) ? tot[t] : 0;
  s[t] = v;
  __syncthreads();
  for (int off = 1; off < 1024; off <<= 1) {
    u32 a = (t >= off) ? s[t - off] : 0;
    __syncthreads();
    s[t] += a;
    __syncthreads();
  }
  if (t < NBKT) est[t] = s[t] - v;
  if (t == NBKT - 1) est[NBKT] = s[t];
}

// passB-S: scatter src low-bits to src-bucket-ordered u8 via LDS cursors
__global__ __launch_bounds__(256) void k_passbS(
    const int* __restrict__ src, const u32* __restrict__ histgS,
    const u32* __restrict__ sstart, u8* __restrict__ lo8) {
  __shared__ u32 cur[1024];
  int pb = blockIdx.x, t = threadIdx.x;
  for (int i = t; i < 1024; i += 256)
    cur[i] = ((i < NBKT) ? sstart[i] : 0u) + histgS[(size_t)pb * 1024 + i];
  __syncthreads();
  int e0 = pb * PA_EPB;
  for (int e = e0 + t; e < e0 + PA_EPB; e += 256) {
    int s = src[e];
    u32 pos = atomicAdd(&cur[s >> 7], 1u);   // LDS atomic
    lo8[pos] = (u8)(s & 127);
  }
}

// countS: per src bucket, 128-bin LDS histogram -> out_norm
__global__ __launch_bounds__(256) void k_countS(const u8* __restrict__ lo8,
                                                const u32* __restrict__ sstart,
                                                float* __restrict__ out_norm) {
  __shared__ u32 cnt[128];
  int k = blockIdx.x, t = threadIdx.x;
  if (t < 128) cnt[t] = 0;
  __syncthreads();
  int e0 = (int)sstart[k], e1 = (int)sstart[k + 1];
  for (int e = e0 + t; e < e1; e += 256) atomicAdd(&cnt[lo8[e]], 1u);
  __syncthreads();
  if (t < 128) {
    int node = k * 128 + t;
    if (node < NN) out_norm[node] = inv_sqrt_cnt((int)cnt[t]);
  }
}

// passB-D: scatter edges to dst-bucket-ordered arrays, folding w = e_w * out_norm[src]
__global__ __launch_bounds__(256) void k_passbD(
    const int* __restrict__ src, const int* __restrict__ dst,
    const float* __restrict__ e_w, const float* __restrict__ out_norm,
    const u32* __restrict__ histgD, const u32* __restrict__ estartD,
    u32* __restrict__ csr_stage, u8* __restrict__ dl8) {
  __shared__ u32 cur[1024];
  int pb = blockIdx.x, t = threadIdx.x;
  for (int i = t; i < 1024; i += 256)
    cur[i] = ((i < NBKT) ? estartD[i] : 0u) + histgD[(size_t)pb * 1024 + i];
  __syncthreads();
  int e0 = pb * PA_EPB;
  for (int e = e0 + t; e < e0 + PA_EPB; e += 256) {
    int s = src[e], d = dst[e];
    float w = e_w[e] * out_norm[s];          // w in (0,1] -> bf16 fits 15 bits
    u32 pos = atomicAdd(&cur[d >> 7], 1u);   // LDS atomic
    csr_stage[pos] = (((u32)f2bf(w)) << 17) | (u32)s;
    dl8[pos] = (u8)(d & 127);
  }
}

// within-bucket counting sort -> per-node CSR + row_start + in_norm
__global__ __launch_bounds__(256) void k_reorder(
    const u32* __restrict__ csr_stage, const u8* __restrict__ dl8,
    const u32* __restrict__ estart, u32* __restrict__ csr,
    int* __restrict__ row_start, float* __restrict__ in_norm) {
  __shared__ u32 cnt[128], pfx[128], cur[128];
  int k = blockIdx.x, t = threadIdx.x;
  if (t < 128) cnt[t] = 0;
  __syncthreads();
  int e0 = (int)estart[k], e1 = (int)estart[k + 1];
  for (int e = e0 + t; e < e1; e += 256) atomicAdd(&cnt[dl8[e]], 1u);
  __syncthreads();
  if (t < 128) pfx[t] = cnt[t];
  __syncthreads();
  for (int off = 1; off < 128; off <<= 1) {
    u32 v = (t < 128 && t >= off) ? pfx[t - off] : 0;
    __syncthreads();
    if (t < 128) pfx[t] += v;
    __syncthreads();
  }
  if (t < 128) {
    u32 start = (u32)e0 + pfx[t] - cnt[t];   // exclusive
    cur[t] = start;
    int node = k * 128 + t;
    if (node < NN) {
      row_start[node] = (int)start;
      in_norm[node] = inv_sqrt_cnt((int)cnt[t]);
    }
  }
  if (k == NBKT - 1 && t == 0) row_start[NN] = e1;
  __syncthreads();
  for (int e = e0 + t; e < e1; e += 256) {
    u32 pos = atomicAdd(&cur[dl8[e]], 1u);
    csr[pos] = csr_stage[e];
  }
}

// agg (proven gather form): aggn[d] = in_norm[d] * sum w_packed * h[src]
__global__ __launch_bounds__(256) void k_agg(const u16* __restrict__ hcat_in,
                                             const int* __restrict__ row_start,
                                             const float* __restrict__ in_norm,
                                             const u32* __restrict__ csr,
                                             u16* __restrict__ hcat_out) {
  int t = threadIdx.x;
  int node = blockIdx.x * 8 + (t >> 5);
  if (node >= NN) return;
  int lane = t & 31;
  int s0 = row_start[node], s1 = row_start[node + 1];
  float ax = 0.f, ay = 0.f, az = 0.f, aw = 0.f;
  for (int i0 = s0; i0 < s1; i0 += 32) {
    u32 pk = 0;
    if (i0 + lane < s1) pk = csr[i0 + lane];
    int m = s1 - i0; if (m > 32) m = 32;
    for (int j = 0; j < m; ++j) {
      u32 p = __shfl(pk, j, 32);
      float w = bf2f((u16)(p >> 17));
      int sv = (int)(p & 0x1FFFF);
      ushort4 hv = *(const ushort4*)(hcat_in + (size_t)sv * HC + lane * 4);
      ax = fmaf(w, bf2f(hv.x), ax);
      ay = fmaf(w, bf2f(hv.y), ay);
      az = fmaf(w, bf2f(hv.z), az);
      aw = fmaf(w, bf2f(hv.w), aw);
    }
  }
  float inn = in_norm[node];
  ushort4 r;
  r.x = f2bf(ax * inn); r.y = f2bf(ay * inn);
  r.z = f2bf(az * inn); r.w = f2bf(aw * inn);
  *(ushort4*)(hcat_out + (size_t)node * HC + HID + lane * 4) = r;
}

// ---------- MFMA layer GEMM (128x128, K=256), optional fused FC ----------
template<int FC>
__global__ __launch_bounds__(512) void k_layer(u16* __restrict__ hcat,
    const u16* __restrict__ WT, const float* __restrict__ bias,
    const float* __restrict__ in_norm,
    const u16* __restrict__ WfcT, const float* __restrict__ b_fc,
    float* __restrict__ out) {
  __shared__ char smem[135168];
  const int t = threadIdx.x;
  const int r0 = blockIdx.x * LBLK;

  #pragma unroll
  for (int i = 0; i < 8; ++i) {      // stage X (64KB); tail OOB rows land in weights scratch, benign
    int boff = i * 8192 + t * 16;
    int row = boff >> 9, col = boff & 511;
    uint4 v = *(const uint4*)(hcat + (size_t)(r0 + row) * HC + (col >> 1));
    *(uint4*)(smem + row * 512 + (col ^ ((row & 7) << 4))) = v;
  }
  #pragma unroll
  for (int i = 0; i < 8; ++i) {      // stage W (64KB)
    int boff = i * 8192 + t * 16;
    int row = boff >> 9, col = boff & 511;
    uint4 v = *(const uint4*)(WT + (size_t)row * 256 + (col >> 1));
    *(uint4*)(smem + 65536 + row * 512 + (col ^ ((row & 7) << 4))) = v;
  }
  if (FC && t < 256) {               // stage WfcT (4KB)
    int row = t >> 4, col = (t & 15) * 16;
    uint4 v = *(const uint4*)(WfcT + (size_t)row * 128 + (col >> 1));
    *(uint4*)(smem + 131072 + row * 256 + (col ^ ((row & 7) << 4))) = v;
  }
  __syncthreads();

  const int lane = t & 63, w = t >> 6;
  const int l15 = lane & 15, lhi = lane >> 4;

  f32x4 acc[8];
  #pragma unroll
  for (int nf = 0; nf < 8; ++nf) acc[nf] = (f32x4){0.f, 0.f, 0.f, 0.f};

  const int arow = w * 16 + l15;
  const char* pa = smem + arow * 512;
  const int aswz = (arow & 7) << 4;
  #pragma unroll
  for (int ks = 0; ks < 8; ++ks) {
    int kb = ks * 64 + (lhi << 4);
    short8 a = *(const short8*)(pa + (kb ^ aswz));
    #pragma unroll
    for (int nf = 0; nf < 8; ++nf) {
      int brow = nf * 16 + l15;
      short8 bf = *(const short8*)(smem + 65536 + brow * 512 + (kb ^ ((brow & 7) << 4)));
      acc[nf] = __builtin_amdgcn_mfma_f32_16x16x32_bf16(a, bf, acc[nf], 0, 0, 0);
    }
  }

  float bcol[8];
  #pragma unroll
  for (int nf = 0; nf < 8; ++nf) bcol[nf] = bias[nf * 16 + l15];

  if (!FC) {
    #pragma unroll
    for (int r = 0; r < 4; ++r) {
      int grow = r0 + w * 16 + (lhi << 2) + r;
      if (grow < NN) {
        float inn = in_norm[grow];
        #pragma unroll
        for (int nf = 0; nf < 8; ++nf) {
          float v = acc[nf][r] + inn * bcol[nf];
          hcat[(size_t)grow * HC + nf * 16 + l15] = f2bf(fmaxf(v, 0.f));
        }
      }
    }
  } else {
    #pragma unroll
    for (int r = 0; r < 4; ++r) {
      int lrow = w * 16 + (lhi << 2) + r;
      int grow = r0 + lrow;
      float inn = (grow < NN) ? in_norm[grow] : 0.f;
      #pragma unroll
      for (int nf = 0; nf < 8; ++nf) {
        int col = nf * 16 + l15;
        float v = fmaxf(acc[nf][r] + inn * bcol[nf], 0.f);
        *(u16*)(smem + lrow * 256 + ((col * 2) ^ ((lrow & 7) << 4))) = f2bf(v);
      }
    }
    __syncthreads();
    f32x4 a2 = (f32x4){0.f, 0.f, 0.f, 0.f};
    const char* pa2 = smem + (w * 16 + l15) * 256;
    const int as2 = (l15 & 7) << 4;
    #pragma unroll
    for (int ks = 0; ks < 4; ++ks) {
      int kb = ks * 64 + (lhi << 4);
      short8 a = *(const short8*)(pa2 + (kb ^ as2));
      short8 bf = *(const short8*)(smem + 131072 + l15 * 256 + (kb ^ as2));
      a2 = __builtin_amdgcn_mfma_f32_16x16x32_bf16(a, bf, a2, 0, 0, 0);
    }
    if (l15 < OUT_F) {
      float bo = b_fc[l15];
      #pragma unroll
      for (int r = 0; r < 4; ++r) {
        int grow = r0 + w * 16 + (lhi << 2) + r;
        if (grow < NN) out[(size_t)grow * OUT_F + l15] = a2[r] + bo;
      }
    }
  }
}

extern "C" void kernel_launch(void* const* d_in, const int* in_sizes, int n_in,
                              void* d_out, int out_size, void* d_ws, size_t ws_size,
                              hipStream_t stream) {
  (void)in_sizes; (void)n_in; (void)out_size;
  const float* inputs  = (const float*)d_in[0];
  const int*   src     = (const int*)d_in[1];
  const int*   dst     = (const int*)d_in[2];
  const float* e_w     = (const float*)d_in[3];
  const float* W_emb   = (const float*)d_in[6];
  const float* b_emb   = (const float*)d_in[7];
  const float* W_self1 = (const float*)d_in[8];
  const float* W1      = (const float*)d_in[9];
  const float* b1      = (const float*)d_in[10];
  const float* W_self2 = (const float*)d_in[11];
  const float* W2      = (const float*)d_in[12];
  const float* b2      = (const float*)d_in[13];
  const float* W_fc    = (const float*)d_in[14];
  const float* b_fc    = (const float*)d_in[15];
  float* out = (float*)d_out;

  // layout (71.1 MB total, < proven 72.2 MB):
  // [histgD 2M | histgS 2M | totalsD 4K | estartD 4K | totalsS 4K | sstart 4K
  //  | out_norm | in_norm | row_start | lo8 u8 EE (shared sl8/dl8)
  //  | csr_stage u32 EE | csr u32 EE | hcat 51.2M | WT1 | WT2 | WfcT]
  u32* histgD      = (u32*)d_ws;
  u32* histgS      = histgD + (size_t)512 * 1024;
  u32* totalsD     = histgS + (size_t)512 * 1024;
  u32* estartD     = totalsD + 1024;
  u32* totalsS     = estartD + 1024;
  u32* sstart      = totalsS + 1024;
  float* out_norm  = (float*)(sstart + 1024);
  float* in_norm   = out_norm + NN;
  int* row_start   = (int*)(in_norm + NN);
  u8* lo8          = (u8*)(row_start + NN + 4);   // sl8 then dl8 (disjoint lifetimes)
  u32* csr_stage   = (u32*)(lo8 + EE);
  u32* csr         = csr_stage + EE;
  u16* hcat        = (u16*)(csr + EE);
  u16* WT1         = hcat + (size_t)NN * HC;
  u16* WT2         = WT1 + 32768;
  u16* WfcT        = WT2 + 32768;

  const size_t NEED = (size_t)2 * 512 * 1024 * 4 + 4096 * 4 + (size_t)(3 * NN + 4) * 4
                      + (size_t)EE * 9 + (size_t)NN * HC * 2 + (2 * 32768 + 2048) * 2;
  if (ws_size < NEED) return;

  hipLaunchKernelGGL(k1, dim3(K1_GRID), dim3(256), 0, stream,
                     src, dst, histgD, histgS, inputs, W_emb, b_emb, hcat,
                     W_self1, W1, W_self2, W2, W_fc, WT1, WT2, WfcT);
  hipLaunchKernelGGL(k_scan1, dim3(2 * NBKT), dim3(256), 0, stream,
                     histgD, histgS, totalsD, totalsS);
  hipLaunchKernelGGL(k_scan2, dim3(2), dim3(1024), 0, stream,
                     totalsD, totalsS, estartD, sstart);
  hipLaunchKernelGGL(k_passbS, dim3(PA_BLKS), dim3(256), 0, stream,
                     src, histgS, sstart, lo8);
  hipLaunchKernelGGL(k_countS, dim3(NBKT), dim3(256), 0, stream, lo8, sstart, out_norm);
  hipLaunchKernelGGL(k_passbD, dim3(PA_BLKS), dim3(256), 0, stream,
                     src, dst, e_w, out_norm, histgD, estartD, csr_stage, lo8);
  hipLaunchKernelGGL(k_reorder, dim3(NBKT), dim3(256), 0, stream,
                     csr_stage, lo8, estartD, csr, row_start, in_norm);
  // layer 1
  hipLaunchKernelGGL(k_agg, dim3((NN + 7) / 8), dim3(256), 0, stream,
                     hcat, row_start, in_norm, csr, hcat);
  hipLaunchKernelGGL(k_layer<0>, dim3((NN + LBLK - 1) / LBLK), dim3(512), 0, stream,
                     hcat, WT1, b1, in_norm, WfcT, b_fc, out);
  // layer 2 + fused FC
  hipLaunchKernelGGL(k_agg, dim3((NN + 7) / 8), dim3(256), 0, stream,
                     hcat, row_start, in_norm, csr, hcat);
  hipLaunchKernelGGL(k_layer<1>, dim3((NN + LBLK - 1) / LBLK), dim3(512), 0, stream,
                     hcat, WT2, b2, in_norm, WfcT, b_fc, out);
}

// Round 8
// 352.776 us; speedup vs baseline: 8.1224x; 1.0801x over previous
//
#include <hip/hip_runtime.h>

#define NN 100000
#define EE 1600000
#define IN_F 24
#define HID 128
#define OUT_F 12
#define LBLK 128        // rows per layer-GEMM block

#define NBKT 782        // node buckets of 128: ceil(NN/128)
#define PA_BLKS 512     // bucket-sort blocks
#define PA_EPB 3125     // EE / PA_BLKS

#define EMB_B 2048
#define PREP_B 264      // (65536 + 2048)/256
#define K1_GRID (PA_BLKS + EMB_B + PREP_B)   // 2824

typedef unsigned char u8;
typedef unsigned short u16;
typedef unsigned int u32;

using short8 = __attribute__((ext_vector_type(8))) short;
using f32x4  = __attribute__((ext_vector_type(4))) float;

__device__ __forceinline__ float bf2f(u16 h) {
  return __uint_as_float(((u32)h) << 16);
}
__device__ __forceinline__ u16 f2bf(float f) {
  u32 u = __float_as_uint(f);
  u32 r = (u + 0x7FFFu + ((u >> 16) & 1u)) >> 16;   // RNE
  return (u16)r;
}
__device__ __forceinline__ float inv_sqrt_cnt(int c) {
  if (c < 1) c = 1;
  return 1.0f / sqrtf((float)c);
}

// ---------- K1 sub-bodies ----------
__device__ __forceinline__ void emb_body(int eb, const float* __restrict__ inputs,
                                         const float* __restrict__ W_emb,
                                         const float* __restrict__ b_emb,
                                         u16* __restrict__ harr, float* smemW) {
  int t = threadIdx.x;
  float* Wls = smemW;
  float* bls = smemW + IN_F * HID;
  for (int i = t; i < IN_F * HID; i += 256) Wls[i] = W_emb[i];
  if (t < HID) bls[t] = b_emb[t];
  __syncthreads();
  int c = t & 127;
  int sub = t >> 7;
  for (int node = eb * 2 + sub; node < NN; node += EMB_B * 2) {
    const float* xr = inputs + (size_t)node * IN_F;
    float acc = bls[c];
    #pragma unroll
    for (int k = 0; k < IN_F; ++k) acc = fmaf(xr[k], Wls[k * HID + c], acc);
    harr[(size_t)node * HID + c] = f2bf(acc);
  }
}

__device__ __forceinline__ void prep_body(int pb,
    const float* __restrict__ Ws1, const float* __restrict__ W1m,
    const float* __restrict__ Ws2, const float* __restrict__ W2m,
    const float* __restrict__ Wfc,
    u16* __restrict__ WT1, u16* __restrict__ WT2, u16* __restrict__ WfcT) {
  int idx = pb * 256 + (int)threadIdx.x;
  if (idx < 65536) {
    int layer = idx >> 15;
    int rem = idx & 32767;
    int n = rem >> 8, k = rem & 255;
    const float* A = layer ? Ws2 : Ws1;
    const float* B = layer ? W2m : W1m;
    float v = (k < HID) ? A[(size_t)k * HID + n] : B[(size_t)(k - HID) * HID + n];
    (layer ? WT2 : WT1)[(size_t)n * 256 + k] = f2bf(v);
  } else if (idx < 65536 + 2048) {
    int j = idx - 65536;
    int n = j >> 7, k = j & 127;
    WfcT[(size_t)n * 128 + k] = f2bf(n < OUT_F ? Wfc[(size_t)k * OUT_F + n] : 0.f);
  }
}

// K1: fused [bucket-count passA (dst AND src hists) | emb | weight prep]
__global__ __launch_bounds__(256) void k1(
    const int* __restrict__ src, const int* __restrict__ dst,
    u32* __restrict__ histgD, u32* __restrict__ histgS,
    const float* __restrict__ inputs, const float* __restrict__ W_emb,
    const float* __restrict__ b_emb, u16* __restrict__ harr,
    const float* __restrict__ Ws1, const float* __restrict__ W1m,
    const float* __restrict__ Ws2, const float* __restrict__ W2m,
    const float* __restrict__ Wfc,
    u16* __restrict__ WT1, u16* __restrict__ WT2, u16* __restrict__ WfcT) {
  __shared__ __align__(16) char sm[13312];
  int b = blockIdx.x, t = threadIdx.x;
  if (b < PA_BLKS) {
    u32* histD = (u32*)sm;
    u32* histS = histD + 1024;
    for (int i = t; i < 2048; i += 256) histD[i] = 0;
    __syncthreads();
    int e0 = b * PA_EPB;
    for (int e = e0 + t; e < e0 + PA_EPB; e += 256) {
      atomicAdd(&histD[dst[e] >> 7], 1u);
      atomicAdd(&histS[src[e] >> 7], 1u);
    }
    __syncthreads();
    for (int i = t; i < 1024; i += 256) {
      histgD[(size_t)b * 1024 + i] = histD[i];
      histgS[(size_t)b * 1024 + i] = histS[i];
    }
  } else if (b < PA_BLKS + EMB_B) {
    emb_body(b - PA_BLKS, inputs, W_emb, b_emb, harr, (float*)sm);
  } else {
    prep_body(b - PA_BLKS - EMB_B, Ws1, W1m, Ws2, W2m, Wfc, WT1, WT2, WfcT);
  }
}

// scan1: per bucket k (dst for b<NBKT, src otherwise), exclusive scan over 512 blocks
__global__ __launch_bounds__(256) void k_scan1(u32* __restrict__ histgD,
                                               u32* __restrict__ histgS,
                                               u32* __restrict__ totalsD,
                                               u32* __restrict__ totalsS) {
  __shared__ u32 s[512];
  int b = blockIdx.x, t = threadIdx.x;
  u32* hist = (b < NBKT) ? histgD : histgS;
  u32* tot  = (b < NBKT) ? totalsD : totalsS;
  int k = (b < NBKT) ? b : b - NBKT;
  u32 v0 = hist[(size_t)t * 1024 + k];
  u32 v1 = hist[(size_t)(t + 256) * 1024 + k];
  s[t] = v0; s[t + 256] = v1;
  __syncthreads();
  for (int off = 1; off < 512; off <<= 1) {
    u32 a0 = (t >= off) ? s[t - off] : 0;
    u32 a1 = (t + 256 >= off) ? s[t + 256 - off] : 0;
    __syncthreads();
    s[t] += a0; s[t + 256] += a1;
    __syncthreads();
  }
  hist[(size_t)t * 1024 + k] = s[t] - v0;              // exclusive prefix
  hist[(size_t)(t + 256) * 1024 + k] = s[t + 256] - v1;
  if (t == 255) tot[k] = s[511];
}

// scan2: exclusive scan over bucket totals (block 0: dst->estartD, block 1: src->sstart)
__global__ __launch_bounds__(1024) void k_scan2(const u32* __restrict__ totalsD,
                                                const u32* __restrict__ totalsS,
                                                u32* __restrict__ estartD,
                                                u32* __restrict__ sstart) {
  __shared__ u32 s[1024];
  const u32* tot = blockIdx.x ? totalsS : totalsD;
  u32* est       = blockIdx.x ? sstart  : estartD;
  int t = threadIdx.x;
  u32 v = (t < NBKT) ? tot[t] : 0;
  s[t] = v;
  __syncthreads();
  for (int off = 1; off < 1024; off <<= 1) {
    u32 a = (t >= off) ? s[t - off] : 0;
    __syncthreads();
    s[t] += a;
    __syncthreads();
  }
  if (t < NBKT) est[t] = s[t] - v;
  if (t == NBKT - 1) est[NBKT] = s[t];
}

// passB-S: scatter src low-bits to src-bucket-ordered u8 via LDS cursors
__global__ __launch_bounds__(256) void k_passbS(
    const int* __restrict__ src, const u32* __restrict__ histgS,
    const u32* __restrict__ sstart, u8* __restrict__ lo8) {
  __shared__ u32 cur[1024];
  int pb = blockIdx.x, t = threadIdx.x;
  for (int i = t; i < 1024; i += 256)
    cur[i] = ((i < NBKT) ? sstart[i] : 0u) + histgS[(size_t)pb * 1024 + i];
  __syncthreads();
  int e0 = pb * PA_EPB;
  for (int e = e0 + t; e < e0 + PA_EPB; e += 256) {
    int s = src[e];
    u32 pos = atomicAdd(&cur[s >> 7], 1u);   // LDS atomic
    lo8[pos] = (u8)(s & 127);
  }
}

// countS: per src bucket, 128-bin LDS histogram -> out_norm
__global__ __launch_bounds__(256) void k_countS(const u8* __restrict__ lo8,
                                                const u32* __restrict__ sstart,
                                                float* __restrict__ out_norm) {
  __shared__ u32 cnt[128];
  int k = blockIdx.x, t = threadIdx.x;
  if (t < 128) cnt[t] = 0;
  __syncthreads();
  int e0 = (int)sstart[k], e1 = (int)sstart[k + 1];
  for (int e = e0 + t; e < e1; e += 256) atomicAdd(&cnt[lo8[e]], 1u);
  __syncthreads();
  if (t < 128) {
    int node = k * 128 + t;
    if (node < NN) out_norm[node] = inv_sqrt_cnt((int)cnt[t]);
  }
}

// passB-D: scatter edges to dst-bucket-ordered arrays, folding w = e_w * out_norm[src]
__global__ __launch_bounds__(256) void k_passbD(
    const int* __restrict__ src, const int* __restrict__ dst,
    const float* __restrict__ e_w, const float* __restrict__ out_norm,
    const u32* __restrict__ histgD, const u32* __restrict__ estartD,
    u32* __restrict__ csr_stage, u8* __restrict__ dl8) {
  __shared__ u32 cur[1024];
  int pb = blockIdx.x, t = threadIdx.x;
  for (int i = t; i < 1024; i += 256)
    cur[i] = ((i < NBKT) ? estartD[i] : 0u) + histgD[(size_t)pb * 1024 + i];
  __syncthreads();
  int e0 = pb * PA_EPB;
  for (int e = e0 + t; e < e0 + PA_EPB; e += 256) {
    int s = src[e], d = dst[e];
    float w = e_w[e] * out_norm[s];          // w in (0,1] -> bf16 fits 15 bits
    u32 pos = atomicAdd(&cur[d >> 7], 1u);   // LDS atomic
    csr_stage[pos] = (((u32)f2bf(w)) << 17) | (u32)s;
    dl8[pos] = (u8)(d & 127);
  }
}

// within-bucket counting sort -> per-node CSR + row_start + in_norm
__global__ __launch_bounds__(256) void k_reorder(
    const u32* __restrict__ csr_stage, const u8* __restrict__ dl8,
    const u32* __restrict__ estart, u32* __restrict__ csr,
    int* __restrict__ row_start, float* __restrict__ in_norm) {
  __shared__ u32 cnt[128], pfx[128], cur[128];
  int k = blockIdx.x, t = threadIdx.x;
  if (t < 128) cnt[t] = 0;
  __syncthreads();
  int e0 = (int)estart[k], e1 = (int)estart[k + 1];
  for (int e = e0 + t; e < e1; e += 256) atomicAdd(&cnt[dl8[e]], 1u);
  __syncthreads();
  if (t < 128) pfx[t] = cnt[t];
  __syncthreads();
  for (int off = 1; off < 128; off <<= 1) {
    u32 v = (t < 128 && t >= off) ? pfx[t - off] : 0;
    __syncthreads();
    if (t < 128) pfx[t] += v;
    __syncthreads();
  }
  if (t < 128) {
    u32 start = (u32)e0 + pfx[t] - cnt[t];   // exclusive
    cur[t] = start;
    int node = k * 128 + t;
    if (node < NN) {
      row_start[node] = (int)start;
      in_norm[node] = inv_sqrt_cnt((int)cnt[t]);
    }
  }
  if (k == NBKT - 1 && t == 0) row_start[NN] = e1;
  __syncthreads();
  for (int e = e0 + t; e < e1; e += 256) {
    u32 pos = atomicAdd(&cur[dl8[e]], 1u);
    csr[pos] = csr_stage[e];
  }
}

// agg: aggn[d] = in_norm[d] * sum w_packed * h[src]; gathers from compact harr,
// 4-way unrolled for memory-level parallelism.
__global__ __launch_bounds__(256) void k_agg(const u16* __restrict__ harr,
                                             const int* __restrict__ row_start,
                                             const float* __restrict__ in_norm,
                                             const u32* __restrict__ csr,
                                             u16* __restrict__ aggr) {
  int t = threadIdx.x;
  int node = blockIdx.x * 8 + (t >> 5);
  if (node >= NN) return;
  int lane = t & 31;
  int s0 = row_start[node], s1 = row_start[node + 1];
  float ax = 0.f, ay = 0.f, az = 0.f, aw = 0.f;
  for (int i0 = s0; i0 < s1; i0 += 32) {
    u32 pk = 0;
    if (i0 + lane < s1) pk = csr[i0 + lane];
    int m = s1 - i0; if (m > 32) m = 32;
    int j = 0;
    for (; j + 4 <= m; j += 4) {
      u32 p0 = __shfl(pk, j,     32);
      u32 p1 = __shfl(pk, j + 1, 32);
      u32 p2 = __shfl(pk, j + 2, 32);
      u32 p3 = __shfl(pk, j + 3, 32);
      ushort4 h0 = *(const ushort4*)(harr + (size_t)(p0 & 0x1FFFF) * HID + lane * 4);
      ushort4 h1 = *(const ushort4*)(harr + (size_t)(p1 & 0x1FFFF) * HID + lane * 4);
      ushort4 h2 = *(const ushort4*)(harr + (size_t)(p2 & 0x1FFFF) * HID + lane * 4);
      ushort4 h3 = *(const ushort4*)(harr + (size_t)(p3 & 0x1FFFF) * HID + lane * 4);
      float w0 = bf2f((u16)(p0 >> 17));
      float w1 = bf2f((u16)(p1 >> 17));
      float w2 = bf2f((u16)(p2 >> 17));
      float w3 = bf2f((u16)(p3 >> 17));
      ax = fmaf(w0, bf2f(h0.x), ax); ay = fmaf(w0, bf2f(h0.y), ay);
      az = fmaf(w0, bf2f(h0.z), az); aw = fmaf(w0, bf2f(h0.w), aw);
      ax = fmaf(w1, bf2f(h1.x), ax); ay = fmaf(w1, bf2f(h1.y), ay);
      az = fmaf(w1, bf2f(h1.z), az); aw = fmaf(w1, bf2f(h1.w), aw);
      ax = fmaf(w2, bf2f(h2.x), ax); ay = fmaf(w2, bf2f(h2.y), ay);
      az = fmaf(w2, bf2f(h2.z), az); aw = fmaf(w2, bf2f(h2.w), aw);
      ax = fmaf(w3, bf2f(h3.x), ax); ay = fmaf(w3, bf2f(h3.y), ay);
      az = fmaf(w3, bf2f(h3.z), az); aw = fmaf(w3, bf2f(h3.w), aw);
    }
    for (; j < m; ++j) {
      u32 p = __shfl(pk, j, 32);
      float w = bf2f((u16)(p >> 17));
      ushort4 hv = *(const ushort4*)(harr + (size_t)(p & 0x1FFFF) * HID + lane * 4);
      ax = fmaf(w, bf2f(hv.x), ax); ay = fmaf(w, bf2f(hv.y), ay);
      az = fmaf(w, bf2f(hv.z), az); aw = fmaf(w, bf2f(hv.w), aw);
    }
  }
  float inn = in_norm[node];
  ushort4 r;
  r.x = f2bf(ax * inn); r.y = f2bf(ay * inn);
  r.z = f2bf(az * inn); r.w = f2bf(aw * inn);
  *(ushort4*)(aggr + (size_t)node * HID + lane * 4) = r;
}

// ---------- MFMA layer GEMM (128x128, K=256), optional fused FC ----------
// X rows staged as [h(256B) | agg(256B)] from the two compact arrays.
template<int FC>
__global__ __launch_bounds__(512) void k_layer(u16* __restrict__ harr,
    const u16* __restrict__ aggr,
    const u16* __restrict__ WT, const float* __restrict__ bias,
    const float* __restrict__ in_norm,
    const u16* __restrict__ WfcT, const float* __restrict__ b_fc,
    float* __restrict__ out) {
  __shared__ char smem[135168];
  const int t = threadIdx.x;
  const int r0 = blockIdx.x * LBLK;

  #pragma unroll
  for (int i = 0; i < 4; ++i) {      // stage X h-half (32KB); tail OOB reads land in-ws, benign
    int boff = i * 8192 + t * 16;
    int row = boff >> 8, col = boff & 255;
    uint4 v = *(const uint4*)(harr + (size_t)(r0 + row) * HID + (col >> 1));
    *(uint4*)(smem + row * 512 + (col ^ ((row & 7) << 4))) = v;
  }
  #pragma unroll
  for (int i = 0; i < 4; ++i) {      // stage X agg-half (32KB)
    int boff = i * 8192 + t * 16;
    int row = boff >> 8, col = boff & 255;
    uint4 v = *(const uint4*)(aggr + (size_t)(r0 + row) * HID + (col >> 1));
    *(uint4*)(smem + row * 512 + (256 + (col ^ ((row & 7) << 4)))) = v;
  }
  #pragma unroll
  for (int i = 0; i < 8; ++i) {      // stage W (64KB)
    int boff = i * 8192 + t * 16;
    int row = boff >> 9, col = boff & 511;
    uint4 v = *(const uint4*)(WT + (size_t)row * 256 + (col >> 1));
    *(uint4*)(smem + 65536 + row * 512 + (col ^ ((row & 7) << 4))) = v;
  }
  if (FC && t < 256) {               // stage WfcT (4KB)
    int row = t >> 4, col = (t & 15) * 16;
    uint4 v = *(const uint4*)(WfcT + (size_t)row * 128 + (col >> 1));
    *(uint4*)(smem + 131072 + row * 256 + (col ^ ((row & 7) << 4))) = v;
  }
  __syncthreads();

  const int lane = t & 63, w = t >> 6;
  const int l15 = lane & 15, lhi = lane >> 4;

  f32x4 acc[8];
  #pragma unroll
  for (int nf = 0; nf < 8; ++nf) acc[nf] = (f32x4){0.f, 0.f, 0.f, 0.f};

  const int arow = w * 16 + l15;
  const char* pa = smem + arow * 512;
  const int aswz = (arow & 7) << 4;
  #pragma unroll
  for (int ks = 0; ks < 8; ++ks) {
    int kb = ks * 64 + (lhi << 4);
    // kb in [0,512); X swizzle applied within each 256B half: for kb>=256,
    // (kb ^ aswz) keeps bit 8 set since aswz < 128.  Same formula works.
    short8 a = *(const short8*)(pa + (kb ^ aswz));
    #pragma unroll
    for (int nf = 0; nf < 8; ++nf) {
      int brow = nf * 16 + l15;
      short8 bf = *(const short8*)(smem + 65536 + brow * 512 + (kb ^ ((brow & 7) << 4)));
      acc[nf] = __builtin_amdgcn_mfma_f32_16x16x32_bf16(a, bf, acc[nf], 0, 0, 0);
    }
  }

  float bcol[8];
  #pragma unroll
  for (int nf = 0; nf < 8; ++nf) bcol[nf] = bias[nf * 16 + l15];

  if (!FC) {
    #pragma unroll
    for (int r = 0; r < 4; ++r) {
      int grow = r0 + w * 16 + (lhi << 2) + r;
      if (grow < NN) {
        float inn = in_norm[grow];
        #pragma unroll
        for (int nf = 0; nf < 8; ++nf) {
          float v = acc[nf][r] + inn * bcol[nf];
          harr[(size_t)grow * HID + nf * 16 + l15] = f2bf(fmaxf(v, 0.f));
        }
      }
    }
  } else {
    #pragma unroll
    for (int r = 0; r < 4; ++r) {
      int lrow = w * 16 + (lhi << 2) + r;
      int grow = r0 + lrow;
      float inn = (grow < NN) ? in_norm[grow] : 0.f;
      #pragma unroll
      for (int nf = 0; nf < 8; ++nf) {
        int col = nf * 16 + l15;
        float v = fmaxf(acc[nf][r] + inn * bcol[nf], 0.f);
        *(u16*)(smem + lrow * 256 + ((col * 2) ^ ((lrow & 7) << 4))) = f2bf(v);
      }
    }
    __syncthreads();
    f32x4 a2 = (f32x4){0.f, 0.f, 0.f, 0.f};
    const char* pa2 = smem + (w * 16 + l15) * 256;
    const int as2 = (l15 & 7) << 4;
    #pragma unroll
    for (int ks = 0; ks < 4; ++ks) {
      int kb = ks * 64 + (lhi << 4);
      short8 a = *(const short8*)(pa2 + (kb ^ as2));
      short8 bf = *(const short8*)(smem + 131072 + l15 * 256 + (kb ^ as2));
      a2 = __builtin_amdgcn_mfma_f32_16x16x32_bf16(a, bf, a2, 0, 0, 0);
    }
    if (l15 < OUT_F) {
      float bo = b_fc[l15];
      #pragma unroll
      for (int r = 0; r < 4; ++r) {
        int grow = r0 + w * 16 + (lhi << 2) + r;
        if (grow < NN) out[(size_t)grow * OUT_F + l15] = a2[r] + bo;
      }
    }
  }
}

extern "C" void kernel_launch(void* const* d_in, const int* in_sizes, int n_in,
                              void* d_out, int out_size, void* d_ws, size_t ws_size,
                              hipStream_t stream) {
  (void)in_sizes; (void)n_in; (void)out_size;
  const float* inputs  = (const float*)d_in[0];
  const int*   src     = (const int*)d_in[1];
  const int*   dst     = (const int*)d_in[2];
  const float* e_w     = (const float*)d_in[3];
  const float* W_emb   = (const float*)d_in[6];
  const float* b_emb   = (const float*)d_in[7];
  const float* W_self1 = (const float*)d_in[8];
  const float* W1      = (const float*)d_in[9];
  const float* b1      = (const float*)d_in[10];
  const float* W_self2 = (const float*)d_in[11];
  const float* W2      = (const float*)d_in[12];
  const float* b2      = (const float*)d_in[13];
  const float* W_fc    = (const float*)d_in[14];
  const float* b_fc    = (const float*)d_in[15];
  float* out = (float*)d_out;

  // layout (71.1 MB total, < proven 72.2 MB):
  // [histgD 2M | histgS 2M | totalsD/estartD/totalsS/sstart 16K
  //  | out_norm | in_norm | row_start | lo8 u8 EE | csr_stage u32 EE | csr u32 EE
  //  | harr N*128 u16 (25.6M) | aggr N*128 u16 (25.6M) | WT1 | WT2 | WfcT]
  u32* histgD      = (u32*)d_ws;
  u32* histgS      = histgD + (size_t)512 * 1024;
  u32* totalsD     = histgS + (size_t)512 * 1024;
  u32* estartD     = totalsD + 1024;
  u32* totalsS     = estartD + 1024;
  u32* sstart      = totalsS + 1024;
  float* out_norm  = (float*)(sstart + 1024);
  float* in_norm   = out_norm + NN;
  int* row_start   = (int*)(in_norm + NN);
  u8* lo8          = (u8*)(row_start + NN + 4);   // sl8 then dl8 (disjoint lifetimes)
  u32* csr_stage   = (u32*)(lo8 + EE);
  u32* csr         = csr_stage + EE;
  u16* harr        = (u16*)(csr + EE);
  u16* aggr        = harr + (size_t)NN * HID;
  u16* WT1         = aggr + (size_t)NN * HID;
  u16* WT2         = WT1 + 32768;
  u16* WfcT        = WT2 + 32768;

  const size_t NEED = (size_t)2 * 512 * 1024 * 4 + 4096 * 4 + (size_t)(3 * NN + 4) * 4
                      + (size_t)EE * 9 + (size_t)NN * HID * 4 + (2 * 32768 + 2048) * 2;
  if (ws_size < NEED) return;

  hipLaunchKernelGGL(k1, dim3(K1_GRID), dim3(256), 0, stream,
                     src, dst, histgD, histgS, inputs, W_emb, b_emb, harr,
                     W_self1, W1, W_self2, W2, W_fc, WT1, WT2, WfcT);
  hipLaunchKernelGGL(k_scan1, dim3(2 * NBKT), dim3(256), 0, stream,
                     histgD, histgS, totalsD, totalsS);
  hipLaunchKernelGGL(k_scan2, dim3(2), dim3(1024), 0, stream,
                     totalsD, totalsS, estartD, sstart);
  hipLaunchKernelGGL(k_passbS, dim3(PA_BLKS), dim3(256), 0, stream,
                     src, histgS, sstart, lo8);
  hipLaunchKernelGGL(k_countS, dim3(NBKT), dim3(256), 0, stream, lo8, sstart, out_norm);
  hipLaunchKernelGGL(k_passbD, dim3(PA_BLKS), dim3(256), 0, stream,
                     src, dst, e_w, out_norm, histgD, estartD, csr_stage, lo8);
  hipLaunchKernelGGL(k_reorder, dim3(NBKT), dim3(256), 0, stream,
                     csr_stage, lo8, estartD, csr, row_start, in_norm);
  // layer 1
  hipLaunchKernelGGL(k_agg, dim3((NN + 7) / 8), dim3(256), 0, stream,
                     harr, row_start, in_norm, csr, aggr);
  hipLaunchKernelGGL(k_layer<0>, dim3((NN + LBLK - 1) / LBLK), dim3(512), 0, stream,
                     harr, aggr, WT1, b1, in_norm, WfcT, b_fc, out);
  // layer 2 + fused FC
  hipLaunchKernelGGL(k_agg, dim3((NN + 7) / 8), dim3(256), 0, stream,
                     harr, row_start, in_norm, csr, aggr);
  hipLaunchKernelGGL(k_layer<1>, dim3((NN + LBLK - 1) / LBLK), dim3(512), 0, stream,
                     harr, aggr, WT2, b2, in_norm, WfcT, b_fc, out);
}